// Round 16
// baseline (283.554 us; speedup 1.0000x reference)
//
#include <hip/hip_runtime.h>
#include <hip/hip_bf16.h>

// Problem: B=64, K=512 (KPLUS1=513), D=E=1024
// out[b,k] = softmax_k( sum_e tanh( (z[b,k,:]@Wz)[e] + (u[b,:]@Wu)[e] ) * bias[e] )
// R16: NO-LDS fp16 GEMM — fragments loaded straight from global (L2-hot)
// in the exact MFMA lane layout (16B/lane, 64B segments). Zero barriers,
// zero staging-path traffic (the measured ~10 B/cyc/CU bottleneck of all
// LDS-staged variants). BM=BN=256, 512 thr / 8 waves (2Mx4N), acc[8][4].

typedef __attribute__((ext_vector_type(8))) short short8;
typedef __attribute__((ext_vector_type(8))) _Float16 half8;
typedef __attribute__((ext_vector_type(4))) float f32x4;
typedef unsigned short ushort_t;

__device__ __forceinline__ ushort_t f2bf(float f) {
    unsigned u = __float_as_uint(f);
    unsigned r = u + 0x7FFFu + ((u >> 16) & 1u);
    return (ushort_t)(r >> 16);
}
__device__ __forceinline__ float bf2f(ushort_t h) {
    return __uint_as_float(((unsigned)h) << 16);
}
__device__ __forceinline__ float tanh_fast(float x) {
    float e = __expf(2.f * x);
    return 1.f - 2.f / (e + 1.f);
}

// ---------------------------------------------------------------------------
// Kernel 0 (fast path): z = x[:,1:,:] -> fp16 [32768][1024] (R7-proven flat).
__global__ __launch_bounds__(256) void k_prep_z16(const float* __restrict__ x,
                                                  _Float16* __restrict__ z_h) {
    const int idx8 = blockIdx.x * 256 + threadIdx.x;
    const int m = idx8 >> 7;
    const int c = (idx8 & 127) * 8;
    const int b = m >> 9, k = m & 511;
    const float* src = x + ((size_t)(b * 513 + 1 + k) << 10) + c;
    const float4 v0 = *(const float4*)src;
    const float4 v1 = *(const float4*)(src + 4);
    half8 hv;
    hv[0] = (_Float16)v0.x; hv[1] = (_Float16)v0.y;
    hv[2] = (_Float16)v0.z; hv[3] = (_Float16)v0.w;
    hv[4] = (_Float16)v1.x; hv[5] = (_Float16)v1.y;
    hv[6] = (_Float16)v1.z; hv[7] = (_Float16)v1.w;
    *(half8*)(z_h + (size_t)m * 1024 + c) = hv;
}

// ---------------------------------------------------------------------------
// Kernel 1 (fast path): transpose Wz ([d][e], rows 0..1023) -> fp16 wzt [e][d].
__global__ void k_prep_w16(const float* __restrict__ w,
                           _Float16* __restrict__ wzt) {
    __shared__ _Float16 th[64][66];
    const int k0 = blockIdx.x * 64;
    const int n0 = blockIdx.y * 64;
    const int t = threadIdx.x;
    const int lr = t >> 6;
    const int lc = t & 63;
#pragma unroll
    for (int r = 0; r < 16; ++r) {
        int kk = r * 4 + lr;
        th[kk][lc] = (_Float16)w[(size_t)(k0 + kk) * 1024 + n0 + lc];
    }
    __syncthreads();
#pragma unroll
    for (int r = 0; r < 16; ++r) {
        int nn = r * 4 + lr;
        wzt[(size_t)(n0 + nn) * 1024 + k0 + lc] = th[lc][nn];
    }
}

// ---------------------------------------------------------------------------
// Kernel 2: hu[b][e] = sum_d u[b][d] * Wu[d][e], exact fp32.
__global__ void k_hu(const float* __restrict__ x,
                     const float* __restrict__ w,
                     float* __restrict__ hu) {
    __shared__ float us[1024];
    const int b = blockIdx.y;
    const int e = blockIdx.x * 256 + threadIdx.x;
    for (int i = threadIdx.x; i < 1024; i += 256)
        us[i] = x[(size_t)b * 513 * 1024 + i];
    __syncthreads();
    const float* wu = w + (size_t)1024 * 1024;
    float acc = 0.f;
#pragma unroll 8
    for (int d = 0; d < 1024; ++d)
        acc = fmaf(us[d], wu[(size_t)d * 1024 + e], acc);
    hu[b * 1024 + e] = acc;
}

// ---------------------------------------------------------------------------
// Kernel 3 (fast path): NO-LDS fp16 GEMM. BM=BN=256, 512 thr / 8 waves
// (2Mx4N), wave = 128x64, acc[8][4]. Per K-step: 8 A-frag + 4 B-frag
// global loads (16B/lane, directly in MFMA layout) + 32 MFMA. No sync.
__global__ __launch_bounds__(512) void k_gemm14(
        const _Float16* __restrict__ z_h,
        const _Float16* __restrict__ wzt,
        const float* __restrict__ hu,
        const float* __restrict__ bias,
        float* __restrict__ qp) {
    __shared__ float qred[2][4][128];   // epilogue only (4 KiB)

    const int t = threadIdx.x;          // 0..511
    const int mtile = blockIdx.x;       // 0..127 (256 rows)
    const int ntile = blockIdx.y;       // 0..3   (256 cols)
    const int wid = t >> 6;
    const int l = t & 63;
    const int wm = wid >> 2;            // 0..1 -> rows wm*128
    const int wn = wid & 3;             // 0..3 -> cols wn*64
    const int lr = l & 15;
    const int g = l >> 4;               // k-chunk 0..3

    // Fragment base pointers: lane l covers row(+lr), k-chunk g (8 fp16=16B).
    const _Float16* aBase = z_h + (size_t)(mtile * 256 + wm * 128 + lr) * 1024 + g * 8;
    const _Float16* bBase = wzt + (size_t)(ntile * 256 + wn * 64 + lr) * 1024 + g * 8;

    f32x4 acc[8][4] = {};

#pragma unroll 4
    for (int k0 = 0; k0 < 1024; k0 += 32) {
        half8 afr[8], bfr[4];
#pragma unroll
        for (int ni = 0; ni < 4; ++ni)
            bfr[ni] = *(const half8*)(bBase + ni * 16384 + k0);   // +16 rows
#pragma unroll
        for (int mi = 0; mi < 8; ++mi)
            afr[mi] = *(const half8*)(aBase + mi * 16384 + k0);
#pragma unroll
        for (int mi = 0; mi < 8; ++mi)
#pragma unroll
            for (int ni = 0; ni < 4; ++ni)
                acc[mi][ni] = __builtin_amdgcn_mfma_f32_16x16x32_f16(
                    afr[mi], bfr[ni], acc[mi][ni], 0, 0, 0);
    }

    // ---- epilogue: partial q over this wave's 64 e-cols (gemm13-verified) ----
    const int bb = mtile >> 1;          // 256 | 512 -> batch block-uniform
    float hu4[4], bias4[4];
#pragma unroll
    for (int ni = 0; ni < 4; ++ni) {
        int e = ntile * 256 + wn * 64 + ni * 16 + lr;
        hu4[ni] = hu[bb * 1024 + e];
        bias4[ni] = bias[e];
    }
#pragma unroll
    for (int mi = 0; mi < 8; ++mi) {
#pragma unroll
        for (int j = 0; j < 4; ++j) {
            float v = 0.f;
#pragma unroll
            for (int ni = 0; ni < 4; ++ni)
                v += tanh_fast(acc[mi][ni][j] + hu4[ni]) * bias4[ni];
            v += __shfl_xor(v, 1);
            v += __shfl_xor(v, 2);
            v += __shfl_xor(v, 4);
            v += __shfl_xor(v, 8);
            if (lr == 0)
                qred[wm][wn][mi * 16 + g * 4 + j] = v;
        }
    }
    __syncthreads();
    if (t < 256) {
        const int wmr = t >> 7;
        const int rr = t & 127;
        float q = qred[wmr][0][rr] + qred[wmr][1][rr]
                + qred[wmr][2][rr] + qred[wmr][3][rr];
        qp[(size_t)ntile * 32768 + mtile * 256 + t] = q;
    }
}

// ---------------------------------------------------------------------------
// Fallback path (R2-verified): split-bf16, in-loop staging (ws too small).
__global__ void k_prep_w(const float* __restrict__ w,
                         ushort_t* __restrict__ wzt_hi,
                         ushort_t* __restrict__ wzt_lo) {
    __shared__ ushort_t th[64][66];
    __shared__ ushort_t tl[64][66];
    const int k0 = blockIdx.x * 64;
    const int n0 = blockIdx.y * 64;
    const int t = threadIdx.x;
    const int lr = t >> 6;
    const int lc = t & 63;
#pragma unroll
    for (int r = 0; r < 16; ++r) {
        int kk = r * 4 + lr;
        float f = w[(size_t)(k0 + kk) * 1024 + n0 + lc];
        ushort_t hi = f2bf(f);
        ushort_t lo = f2bf(f - bf2f(hi));
        th[kk][lc] = hi;
        tl[kk][lc] = lo;
    }
    __syncthreads();
#pragma unroll
    for (int r = 0; r < 16; ++r) {
        int nn = r * 4 + lr;
        wzt_hi[(size_t)(n0 + nn) * 1024 + k0 + lc] = th[lc][nn];
        wzt_lo[(size_t)(n0 + nn) * 1024 + k0 + lc] = tl[lc][nn];
    }
}

__global__ __launch_bounds__(256) void k_gemm(
        const float* __restrict__ x,
        const ushort_t* __restrict__ wzt_hi,
        const ushort_t* __restrict__ wzt_lo,
        const float* __restrict__ hu,
        const float* __restrict__ bias,
        float* __restrict__ qp) {
    __shared__ ushort_t As_hi[128][40];
    __shared__ ushort_t As_lo[128][40];
    __shared__ ushort_t Bs_hi[128][40];
    __shared__ ushort_t Bs_lo[128][40];
    __shared__ float qred[2][2][64];

    const int t = threadIdx.x;
    const int mtile = blockIdx.x;
    const int ntile = blockIdx.y;
    const int wid = t >> 6;
    const int l = t & 63;
    const int wm = wid >> 1;
    const int wn = wid & 1;

    f32x4 acc[4][4] = {};

    const int arow = t >> 3;
    const int acol = (t & 7) * 4;
    size_t abase[4];
#pragma unroll
    for (int it = 0; it < 4; ++it) {
        int m = mtile * 128 + arow + it * 32;
        int bb = m >> 9;
        int kk = m & 511;
        abase[it] = ((size_t)(bb * 513 + 1 + kk)) * 1024 + acol;
    }
    const int brow = t >> 2;
    const int bcol = (t & 3) * 8;
    const size_t bbase = (size_t)(ntile * 128 + brow) * 1024 + bcol;

    for (int k0 = 0; k0 < 1024; k0 += 32) {
#pragma unroll
        for (int it = 0; it < 4; ++it) {
            const float4 v = *(const float4*)(x + abase[it] + k0);
            ushort4 hv, lv;
            hv.x = f2bf(v.x); lv.x = f2bf(v.x - bf2f(hv.x));
            hv.y = f2bf(v.y); lv.y = f2bf(v.y - bf2f(hv.y));
            hv.z = f2bf(v.z); lv.z = f2bf(v.z - bf2f(hv.z));
            hv.w = f2bf(v.w); lv.w = f2bf(v.w - bf2f(hv.w));
            const int row = arow + it * 32;
            *(ushort4*)&As_hi[row][acol] = hv;
            *(ushort4*)&As_lo[row][acol] = lv;
        }
#pragma unroll
        for (int it = 0; it < 2; ++it) {
            const int row = brow + it * 64;
            const uint4 vh = *(const uint4*)(wzt_hi + bbase + (size_t)it * 64 * 1024 + k0);
            const uint4 vl = *(const uint4*)(wzt_lo + bbase + (size_t)it * 64 * 1024 + k0);
            *(uint4*)&Bs_hi[row][bcol] = vh;
            *(uint4*)&Bs_lo[row][bcol] = vl;
        }
        __syncthreads();

        const int lr = l & 15;
        const int lk = (l >> 4) * 8;
        short8 ah[4], al[4], bh[4], bl[4];
#pragma unroll
        for (int i = 0; i < 4; ++i) {
            ah[i] = *(const short8*)&As_hi[wm * 64 + i * 16 + lr][lk];
            al[i] = *(const short8*)&As_lo[wm * 64 + i * 16 + lr][lk];
            bh[i] = *(const short8*)&Bs_hi[wn * 64 + i * 16 + lr][lk];
            bl[i] = *(const short8*)&Bs_lo[wn * 64 + i * 16 + lr][lk];
        }
#pragma unroll
        for (int mi = 0; mi < 4; ++mi)
#pragma unroll
            for (int ni = 0; ni < 4; ++ni) {
                acc[mi][ni] = __builtin_amdgcn_mfma_f32_16x16x32_bf16(ah[mi], bh[ni], acc[mi][ni], 0, 0, 0);
                acc[mi][ni] = __builtin_amdgcn_mfma_f32_16x16x32_bf16(ah[mi], bl[ni], acc[mi][ni], 0, 0, 0);
                acc[mi][ni] = __builtin_amdgcn_mfma_f32_16x16x32_bf16(al[mi], bh[ni], acc[mi][ni], 0, 0, 0);
            }
        __syncthreads();
    }

    const int lr = l & 15;
    const int lg = l >> 4;
    const int bbatch = mtile >> 2;
    float hu4[4], bias4[4];
#pragma unroll
    for (int ni = 0; ni < 4; ++ni) {
        int e = ntile * 128 + wn * 64 + ni * 16 + lr;
        hu4[ni] = hu[bbatch * 1024 + e];
        bias4[ni] = bias[e];
    }
#pragma unroll
    for (int mi = 0; mi < 4; ++mi) {
#pragma unroll
        for (int j = 0; j < 4; ++j) {
            float v = 0.f;
#pragma unroll
            for (int ni = 0; ni < 4; ++ni)
                v += tanhf(acc[mi][ni][j] + hu4[ni]) * bias4[ni];
            v += __shfl_xor(v, 1);
            v += __shfl_xor(v, 2);
            v += __shfl_xor(v, 4);
            v += __shfl_xor(v, 8);
            if (lr == 0)
                qred[wm][wn][mi * 16 + lg * 4 + j] = v;
        }
    }
    __syncthreads();
    if (t < 128) {
        const int wmr = t >> 6;
        const int rr = t & 63;
        float qv = qred[wmr][0][rr] + qred[wmr][1][rr];
        qp[(size_t)ntile * 32768 + mtile * 128 + t] = qv;
    }
}

// ---------------------------------------------------------------------------
// Kernel 4: reduce partials over nt tiles + softmax over k (512) per batch.
__global__ void k_softmax(const float* __restrict__ qp, float* __restrict__ out,
                          int nt) {
    const int b = blockIdx.x;
    const int k = threadIdx.x;   // 512 threads
    float q = 0.f;
    for (int i = 0; i < nt; ++i)
        q += qp[(size_t)i * 32768 + b * 512 + k];

    __shared__ float redm[8];
    __shared__ float reds[8];
    const int wid = k >> 6;

    float m = q;
#pragma unroll
    for (int off = 32; off >= 1; off >>= 1)
        m = fmaxf(m, __shfl_xor(m, off));
    if ((k & 63) == 0) redm[wid] = m;
    __syncthreads();
    m = redm[0];
#pragma unroll
    for (int i = 1; i < 8; ++i) m = fmaxf(m, redm[i]);

    float p = expf(q - m);
    float s = p;
#pragma unroll
    for (int off = 32; off >= 1; off >>= 1)
        s += __shfl_xor(s, off);
    if ((k & 63) == 0) reds[wid] = s;
    __syncthreads();
    s = 0.f;
#pragma unroll
    for (int i = 0; i < 8; ++i) s += reds[i];

    out[b * 512 + k] = p / s;
}

// ---------------------------------------------------------------------------
extern "C" void kernel_launch(void* const* d_in, const int* in_sizes, int n_in,
                              void* d_out, int out_size, void* d_ws, size_t ws_size,
                              hipStream_t stream) {
    const float* x    = (const float*)d_in[0];   // (64, 513, 1024) f32
    const float* w    = (const float*)d_in[1];   // (2048, 1024) f32
    const float* bias = (const float*)d_in[2];   // (1024, 1) f32
    float* out = (float*)d_out;                  // (64, 512) f32

    char* ws = (char*)d_ws;
    const size_t ZN = (size_t)32768 * 1024;      // z elements

    // fast-path ws: z_h (64MB fp16) + wzt (2MB fp16) + hu (256KB) + qp (512KB)
    const size_t need = ZN * sizeof(_Float16)
                      + (size_t)1024 * 1024 * sizeof(_Float16)
                      + (size_t)64 * 1024 * sizeof(float)
                      + (size_t)4 * 32768 * sizeof(float);

    if (ws_size >= need) {
        _Float16* z_h = (_Float16*)ws;
        _Float16* wzt = z_h + ZN;
        float*    hu  = (float*)(wzt + (size_t)1024 * 1024);
        float*    qp  = hu + (size_t)64 * 1024;

        k_prep_z16<<<16384, 256, 0, stream>>>(x, z_h);
        k_prep_w16<<<dim3(16, 16), 256, 0, stream>>>(w, wzt);
        k_hu<<<dim3(4, 64), 256, 0, stream>>>(x, w, hu);
        k_gemm14<<<dim3(128, 4), 512, 0, stream>>>(z_h, wzt, hu, bias, qp);
        k_softmax<<<64, 512, 0, stream>>>(qp, out, 4);
    } else {
        ushort_t* wzt_hi = (ushort_t*)ws;
        ushort_t* wzt_lo = wzt_hi + (size_t)1024 * 1024;
        float* hu = (float*)(ws + (size_t)4 * 1024 * 1024);
        float* qp = hu + (size_t)64 * 1024;

        k_prep_w<<<dim3(16, 16), 256, 0, stream>>>(w, wzt_hi, wzt_lo);
        k_hu<<<dim3(4, 64), 256, 0, stream>>>(x, w, hu);
        k_gemm<<<dim3(256, 8), 256, 0, stream>>>(x, wzt_hi, wzt_lo, hu, bias, qp);
        k_softmax<<<64, 512, 0, stream>>>(qp, out, 8);
    }
}

// Round 17
// 165.522 us; speedup vs baseline: 1.7131x; 1.7131x over previous
//
#include <hip/hip_runtime.h>
#include <hip/hip_bf16.h>

// Problem: B=64, K=512 (KPLUS1=513), D=E=1024
// out[b,k] = softmax_k( sum_e tanh( (z[b,k,:]@Wz)[e] + (u[b,:]@Wu)[e] ) * bias[e] )
// R17: gemm13 (R15-verified, best LDS-staged GEMM) + merged prep with
// hu-blocks FIRST (R13's merge failed only because hu stragglers were
// scheduled last). One prep dispatch ~35us instead of 46us serialized.

typedef __attribute__((ext_vector_type(8))) short short8;
typedef __attribute__((ext_vector_type(8))) _Float16 half8;
typedef __attribute__((ext_vector_type(4))) float f32x4;
typedef unsigned short ushort_t;

typedef const __attribute__((address_space(1))) void gvoid_t;
typedef __attribute__((address_space(3))) void lvoid_t;

__device__ __forceinline__ ushort_t f2bf(float f) {
    unsigned u = __float_as_uint(f);
    unsigned r = u + 0x7FFFu + ((u >> 16) & 1u);
    return (ushort_t)(r >> 16);
}
__device__ __forceinline__ float bf2f(ushort_t h) {
    return __uint_as_float(((unsigned)h) << 16);
}
__device__ __forceinline__ float tanh_fast(float x) {
    float e = __expf(2.f * x);
    return 1.f - 2.f / (e + 1.f);
}

// ---------------------------------------------------------------------------
// Kernel 0 (fast path): merged prep, hu FIRST so its long blocks overlap the
// z-conversion sweep. Blocks [0,256): hu; [256,512): Wz transpose; [512,
// 16896): z->fp16 (flat, R7-proven pattern).
__global__ __launch_bounds__(256) void k_prep_all2(const float* __restrict__ x,
                                                   const float* __restrict__ w,
                                                   _Float16* __restrict__ z_h,
                                                   _Float16* __restrict__ wzt,
                                                   float* __restrict__ hu) {
    __shared__ float us[1024];
    __shared__ _Float16 th[64][66];
    const int blk = blockIdx.x;
    const int t = threadIdx.x;

    if (blk < 256) {
        // ---- hu[b][e] = sum_d u[b][d]*Wu[d][e] (exact fp32) ----
        const int b = blk >> 2;
        const int e = (blk & 3) * 256 + t;
        for (int i = t; i < 1024; i += 256)
            us[i] = x[(size_t)b * 513 * 1024 + i];
        __syncthreads();
        const float* wu = w + (size_t)1024 * 1024;
        float acc = 0.f;
#pragma unroll 8
        for (int d = 0; d < 1024; ++d)
            acc = fmaf(us[d], wu[(size_t)d * 1024 + e], acc);
        hu[b * 1024 + e] = acc;
    } else if (blk < 512) {
        // ---- Wz ([d][e] rows 0..1023) transpose -> fp16 wzt [e][d] ----
        const int idx = blk - 256;
        const int k0 = (idx & 15) * 64;
        const int n0 = (idx >> 4) * 64;
        const int lr = t >> 6;
        const int lc = t & 63;
#pragma unroll
        for (int r = 0; r < 16; ++r) {
            int kk = r * 4 + lr;
            th[kk][lc] = (_Float16)w[(size_t)(k0 + kk) * 1024 + n0 + lc];
        }
        __syncthreads();
#pragma unroll
        for (int r = 0; r < 16; ++r) {
            int nn = r * 4 + lr;
            wzt[(size_t)(n0 + nn) * 1024 + k0 + lc] = th[lc][nn];
        }
    } else {
        // ---- z = x[:,1:,:] -> fp16 [32768][1024] ----
        const int idx8 = (blk - 512) * 256 + t;
        const int m = idx8 >> 7;
        const int c = (idx8 & 127) * 8;
        const int b = m >> 9, k = m & 511;
        const float* src = x + ((size_t)(b * 513 + 1 + k) << 10) + c;
        const float4 v0 = *(const float4*)src;
        const float4 v1 = *(const float4*)(src + 4);
        half8 hv;
        hv[0] = (_Float16)v0.x; hv[1] = (_Float16)v0.y;
        hv[2] = (_Float16)v0.z; hv[3] = (_Float16)v0.w;
        hv[4] = (_Float16)v1.x; hv[5] = (_Float16)v1.y;
        hv[6] = (_Float16)v1.z; hv[7] = (_Float16)v1.w;
        *(half8*)(z_h + (size_t)m * 1024 + c) = hv;
    }
}

// ---------------------------------------------------------------------------
// Kernel 1 (fast path): fp16 GEMM (R15-verified gemm13). BM=BN=256, BK=32,
// 512 thr / 8 waves (2Mx4N), wave 128x64, acc[8][4]. 3-slot LDS ring
// (32KB/slot), depth-2 prefetch, per step: {12 ds_read || STAGE(T+2)
// 4 gload_lds -> lgkmcnt(0) -> setprio(1) 32 MFMA setprio(0) -> vmcnt(4)
// -> s_barrier}. Swizzle: chunk ^= (row>>1)&3 (both sides, 0 conflicts).
__global__ __launch_bounds__(512) void k_gemm13(
        const _Float16* __restrict__ z_h,
        const _Float16* __restrict__ wzt,
        const float* __restrict__ hu,
        const float* __restrict__ bias,
        float* __restrict__ qp) {
    __shared__ __align__(16) _Float16 lds[3 * 16384];   // 96 KiB
    __shared__ float qred[2][4][128];                   // 4 KiB

    const int t = threadIdx.x;          // 0..511
    const int mtile = blockIdx.x;       // 0..127 (256 rows)
    const int ntile = blockIdx.y;       // 0..3   (256 cols)
    const int wid = t >> 6;
    const int l = t & 63;
    const int wm = wid >> 2;            // 0..1 -> rows wm*128
    const int wn = wid & 3;             // 0..3 -> cols wn*64
    const int lr = l & 15;
    const int g = l >> 4;               // logical k-chunk 0..3

    char* ldsb = (char*)lds;

    const int swz = (g ^ ((lr >> 1) & 3)) * 16;
    const int aOffRd = (wm * 128 + lr) * 64 + swz;            // + mi*1024
    const int bOffRd = 16384 + (wn * 64 + lr) * 64 + swz;     // + ni*1024

    const int schunk = ((t & 3) ^ ((t >> 3) & 3)) * 8;
    size_t aSrc[2], bSrc[2];
#pragma unroll
    for (int j = 0; j < 2; ++j) {
        aSrc[j] = (size_t)(mtile * 256 + (t >> 2) + j * 128) * 1024 + schunk;
        bSrc[j] = (size_t)(ntile * 256 + (t >> 2) + j * 128) * 1024 + schunk;
    }

#define STAGE(kt, SLOT)                                                      \
    {   const int _kc = (kt) * 32;                                           \
        char* _d = ldsb + (SLOT) * 32768;                                    \
        _Pragma("unroll")                                                    \
        for (int j = 0; j < 2; ++j)                                          \
            __builtin_amdgcn_global_load_lds((gvoid_t*)(z_h + aSrc[j] + _kc),\
                (lvoid_t*)(_d + t * 16 + j * 8192), 16, 0, 0);               \
        _Pragma("unroll")                                                    \
        for (int j = 0; j < 2; ++j)                                          \
            __builtin_amdgcn_global_load_lds((gvoid_t*)(wzt + bSrc[j] + _kc),\
                (lvoid_t*)(_d + 16384 + t * 16 + j * 8192), 16, 0, 0); }

#define KBODY(T, SLOT, DOSTAGE, VMSTR)                                       \
    {   char* _sb = ldsb + (SLOT) * 32768;                                   \
        half8 afr[8], bfr[4];                                                \
        _Pragma("unroll")                                                    \
        for (int ni = 0; ni < 4; ++ni)                                       \
            bfr[ni] = *(const half8*)(_sb + bOffRd + ni * 1024);             \
        _Pragma("unroll")                                                    \
        for (int mi = 0; mi < 8; ++mi)                                       \
            afr[mi] = *(const half8*)(_sb + aOffRd + mi * 1024);             \
        if (DOSTAGE) { STAGE((T) + 2, ((SLOT) + 2) % 3); }                   \
        asm volatile("s_waitcnt lgkmcnt(0)" ::: "memory");                   \
        __builtin_amdgcn_sched_barrier(0);                                   \
        __builtin_amdgcn_s_setprio(1);                                       \
        _Pragma("unroll")                                                    \
        for (int mi = 0; mi < 8; ++mi)                                       \
            _Pragma("unroll")                                                \
            for (int ni = 0; ni < 4; ++ni)                                   \
                acc[mi][ni] = __builtin_amdgcn_mfma_f32_16x16x32_f16(        \
                    afr[mi], bfr[ni], acc[mi][ni], 0, 0, 0);                 \
        __builtin_amdgcn_s_setprio(0);                                       \
        asm volatile(VMSTR ::: "memory");                                    \
        __builtin_amdgcn_sched_barrier(0);                                   \
        __builtin_amdgcn_s_barrier(); }

    f32x4 acc[8][4] = {};

    STAGE(0, 0); STAGE(1, 1);
    asm volatile("s_waitcnt vmcnt(4)" ::: "memory");
    __builtin_amdgcn_sched_barrier(0);
    __builtin_amdgcn_s_barrier();

#pragma unroll 1
    for (int i = 0; i < 10; ++i) {
        const int T = i * 3;
        KBODY(T + 0, 0, true, "s_waitcnt vmcnt(4)");
        KBODY(T + 1, 1, true, "s_waitcnt vmcnt(4)");
        KBODY(T + 2, 2, true, "s_waitcnt vmcnt(4)");
    }
    KBODY(30, 0, false, "s_waitcnt vmcnt(0)");
    KBODY(31, 1, false, "s_nop 0");
#undef KBODY
#undef STAGE

    // ---- epilogue ----
    const int bb = mtile >> 1;
    float hu4[4], bias4[4];
#pragma unroll
    for (int ni = 0; ni < 4; ++ni) {
        int e = ntile * 256 + wn * 64 + ni * 16 + lr;
        hu4[ni] = hu[bb * 1024 + e];
        bias4[ni] = bias[e];
    }
#pragma unroll
    for (int mi = 0; mi < 8; ++mi) {
#pragma unroll
        for (int j = 0; j < 4; ++j) {
            float v = 0.f;
#pragma unroll
            for (int ni = 0; ni < 4; ++ni)
                v += tanh_fast(acc[mi][ni][j] + hu4[ni]) * bias4[ni];
            v += __shfl_xor(v, 1);
            v += __shfl_xor(v, 2);
            v += __shfl_xor(v, 4);
            v += __shfl_xor(v, 8);
            if (lr == 0)
                qred[wm][wn][mi * 16 + g * 4 + j] = v;
        }
    }
    __syncthreads();
    if (t < 256) {
        const int wmr = t >> 7;
        const int rr = t & 127;
        float q = qred[wmr][0][rr] + qred[wmr][1][rr]
                + qred[wmr][2][rr] + qred[wmr][3][rr];
        qp[(size_t)ntile * 32768 + mtile * 256 + t] = q;
    }
}

// ---------------------------------------------------------------------------
// Fallback path (R2-verified): split-bf16, in-loop staging (ws too small).
__global__ void k_prep_w(const float* __restrict__ w,
                         ushort_t* __restrict__ wzt_hi,
                         ushort_t* __restrict__ wzt_lo) {
    __shared__ ushort_t th[64][66];
    __shared__ ushort_t tl[64][66];
    const int k0 = blockIdx.x * 64;
    const int n0 = blockIdx.y * 64;
    const int t = threadIdx.x;
    const int lr = t >> 6;
    const int lc = t & 63;
#pragma unroll
    for (int r = 0; r < 16; ++r) {
        int kk = r * 4 + lr;
        float f = w[(size_t)(k0 + kk) * 1024 + n0 + lc];
        ushort_t hi = f2bf(f);
        ushort_t lo = f2bf(f - bf2f(hi));
        th[kk][lc] = hi;
        tl[kk][lc] = lo;
    }
    __syncthreads();
#pragma unroll
    for (int r = 0; r < 16; ++r) {
        int nn = r * 4 + lr;
        wzt_hi[(size_t)(n0 + nn) * 1024 + k0 + lc] = th[lc][nn];
        wzt_lo[(size_t)(n0 + nn) * 1024 + k0 + lc] = tl[lc][nn];
    }
}

__global__ void k_hu(const float* __restrict__ x,
                     const float* __restrict__ w,
                     float* __restrict__ hu) {
    __shared__ float us[1024];
    const int b = blockIdx.y;
    const int e = blockIdx.x * 256 + threadIdx.x;
    for (int i = threadIdx.x; i < 1024; i += 256)
        us[i] = x[(size_t)b * 513 * 1024 + i];
    __syncthreads();
    const float* wu = w + (size_t)1024 * 1024;
    float acc = 0.f;
#pragma unroll 8
    for (int d = 0; d < 1024; ++d)
        acc = fmaf(us[d], wu[(size_t)d * 1024 + e], acc);
    hu[b * 1024 + e] = acc;
}

__global__ __launch_bounds__(256) void k_gemm(
        const float* __restrict__ x,
        const ushort_t* __restrict__ wzt_hi,
        const ushort_t* __restrict__ wzt_lo,
        const float* __restrict__ hu,
        const float* __restrict__ bias,
        float* __restrict__ qp) {
    __shared__ ushort_t As_hi[128][40];
    __shared__ ushort_t As_lo[128][40];
    __shared__ ushort_t Bs_hi[128][40];
    __shared__ ushort_t Bs_lo[128][40];
    __shared__ float qred[2][2][64];

    const int t = threadIdx.x;
    const int mtile = blockIdx.x;
    const int ntile = blockIdx.y;
    const int wid = t >> 6;
    const int l = t & 63;
    const int wm = wid >> 1;
    const int wn = wid & 1;

    f32x4 acc[4][4] = {};

    const int arow = t >> 3;
    const int acol = (t & 7) * 4;
    size_t abase[4];
#pragma unroll
    for (int it = 0; it < 4; ++it) {
        int m = mtile * 128 + arow + it * 32;
        int bb = m >> 9;
        int kk = m & 511;
        abase[it] = ((size_t)(bb * 513 + 1 + kk)) * 1024 + acol;
    }
    const int brow = t >> 2;
    const int bcol = (t & 3) * 8;
    const size_t bbase = (size_t)(ntile * 128 + brow) * 1024 + bcol;

    for (int k0 = 0; k0 < 1024; k0 += 32) {
#pragma unroll
        for (int it = 0; it < 4; ++it) {
            const float4 v = *(const float4*)(x + abase[it] + k0);
            ushort4 hv, lv;
            hv.x = f2bf(v.x); lv.x = f2bf(v.x - bf2f(hv.x));
            hv.y = f2bf(v.y); lv.y = f2bf(v.y - bf2f(hv.y));
            hv.z = f2bf(v.z); lv.z = f2bf(v.z - bf2f(hv.z));
            hv.w = f2bf(v.w); lv.w = f2bf(v.w - bf2f(hv.w));
            const int row = arow + it * 32;
            *(ushort4*)&As_hi[row][acol] = hv;
            *(ushort4*)&As_lo[row][acol] = lv;
        }
#pragma unroll
        for (int it = 0; it < 2; ++it) {
            const int row = brow + it * 64;
            const uint4 vh = *(const uint4*)(wzt_hi + bbase + (size_t)it * 64 * 1024 + k0);
            const uint4 vl = *(const uint4*)(wzt_lo + bbase + (size_t)it * 64 * 1024 + k0);
            *(uint4*)&Bs_hi[row][bcol] = vh;
            *(uint4*)&Bs_lo[row][bcol] = vl;
        }
        __syncthreads();

        const int lr = l & 15;
        const int lk = (l >> 4) * 8;
        short8 ah[4], al[4], bh[4], bl[4];
#pragma unroll
        for (int i = 0; i < 4; ++i) {
            ah[i] = *(const short8*)&As_hi[wm * 64 + i * 16 + lr][lk];
            al[i] = *(const short8*)&As_lo[wm * 64 + i * 16 + lr][lk];
            bh[i] = *(const short8*)&Bs_hi[wn * 64 + i * 16 + lr][lk];
            bl[i] = *(const short8*)&Bs_lo[wn * 64 + i * 16 + lr][lk];
        }
#pragma unroll
        for (int mi = 0; mi < 4; ++mi)
#pragma unroll
            for (int ni = 0; ni < 4; ++ni) {
                acc[mi][ni] = __builtin_amdgcn_mfma_f32_16x16x32_bf16(ah[mi], bh[ni], acc[mi][ni], 0, 0, 0);
                acc[mi][ni] = __builtin_amdgcn_mfma_f32_16x16x32_bf16(ah[mi], bl[ni], acc[mi][ni], 0, 0, 0);
                acc[mi][ni] = __builtin_amdgcn_mfma_f32_16x16x32_bf16(al[mi], bh[ni], acc[mi][ni], 0, 0, 0);
            }
        __syncthreads();
    }

    const int lr = l & 15;
    const int lg = l >> 4;
    const int bbatch = mtile >> 2;
    float hu4[4], bias4[4];
#pragma unroll
    for (int ni = 0; ni < 4; ++ni) {
        int e = ntile * 128 + wn * 64 + ni * 16 + lr;
        hu4[ni] = hu[bbatch * 1024 + e];
        bias4[ni] = bias[e];
    }
#pragma unroll
    for (int mi = 0; mi < 4; ++mi) {
#pragma unroll
        for (int j = 0; j < 4; ++j) {
            float v = 0.f;
#pragma unroll
            for (int ni = 0; ni < 4; ++ni)
                v += tanhf(acc[mi][ni][j] + hu4[ni]) * bias4[ni];
            v += __shfl_xor(v, 1);
            v += __shfl_xor(v, 2);
            v += __shfl_xor(v, 4);
            v += __shfl_xor(v, 8);
            if (lr == 0)
                qred[wm][wn][mi * 16 + lg * 4 + j] = v;
        }
    }
    __syncthreads();
    if (t < 128) {
        const int wmr = t >> 6;
        const int rr = t & 63;
        float qv = qred[wmr][0][rr] + qred[wmr][1][rr];
        qp[(size_t)ntile * 32768 + mtile * 128 + t] = qv;
    }
}

// ---------------------------------------------------------------------------
// Kernel 4: reduce partials over nt tiles + softmax over k (512) per batch.
__global__ void k_softmax(const float* __restrict__ qp, float* __restrict__ out,
                          int nt) {
    const int b = blockIdx.x;
    const int k = threadIdx.x;   // 512 threads
    float q = 0.f;
    for (int i = 0; i < nt; ++i)
        q += qp[(size_t)i * 32768 + b * 512 + k];

    __shared__ float redm[8];
    __shared__ float reds[8];
    const int wid = k >> 6;

    float m = q;
#pragma unroll
    for (int off = 32; off >= 1; off >>= 1)
        m = fmaxf(m, __shfl_xor(m, off));
    if ((k & 63) == 0) redm[wid] = m;
    __syncthreads();
    m = redm[0];
#pragma unroll
    for (int i = 1; i < 8; ++i) m = fmaxf(m, redm[i]);

    float p = expf(q - m);
    float s = p;
#pragma unroll
    for (int off = 32; off >= 1; off >>= 1)
        s += __shfl_xor(s, off);
    if ((k & 63) == 0) reds[wid] = s;
    __syncthreads();
    s = 0.f;
#pragma unroll
    for (int i = 0; i < 8; ++i) s += reds[i];

    out[b * 512 + k] = p / s;
}

// ---------------------------------------------------------------------------
extern "C" void kernel_launch(void* const* d_in, const int* in_sizes, int n_in,
                              void* d_out, int out_size, void* d_ws, size_t ws_size,
                              hipStream_t stream) {
    const float* x    = (const float*)d_in[0];   // (64, 513, 1024) f32
    const float* w    = (const float*)d_in[1];   // (2048, 1024) f32
    const float* bias = (const float*)d_in[2];   // (1024, 1) f32
    float* out = (float*)d_out;                  // (64, 512) f32

    char* ws = (char*)d_ws;
    const size_t ZN = (size_t)32768 * 1024;      // z elements

    // fast-path ws: z_h (64MB fp16) + wzt (2MB fp16) + hu (256KB) + qp (512KB)
    const size_t need = ZN * sizeof(_Float16)
                      + (size_t)1024 * 1024 * sizeof(_Float16)
                      + (size_t)64 * 1024 * sizeof(float)
                      + (size_t)4 * 32768 * sizeof(float);

    if (ws_size >= need) {
        _Float16* z_h = (_Float16*)ws;
        _Float16* wzt = z_h + ZN;
        float*    hu  = (float*)(wzt + (size_t)1024 * 1024);
        float*    qp  = hu + (size_t)64 * 1024;

        k_prep_all2<<<16896, 256, 0, stream>>>(x, w, z_h, wzt, hu);
        k_gemm13<<<dim3(128, 4), 512, 0, stream>>>(z_h, wzt, hu, bias, qp);
        k_softmax<<<64, 512, 0, stream>>>(qp, out, 4);
    } else {
        ushort_t* wzt_hi = (ushort_t*)ws;
        ushort_t* wzt_lo = wzt_hi + (size_t)1024 * 1024;
        float* hu = (float*)(ws + (size_t)4 * 1024 * 1024);
        float* qp = hu + (size_t)64 * 1024;

        k_prep_w<<<dim3(16, 16), 256, 0, stream>>>(w, wzt_hi, wzt_lo);
        k_hu<<<dim3(4, 64), 256, 0, stream>>>(x, w, hu);
        k_gemm<<<dim3(256, 8), 256, 0, stream>>>(x, wzt_hi, wzt_lo, hu, bias, qp);
        k_softmax<<<64, 512, 0, stream>>>(qp, out, 8);
    }
}